// Round 1
// baseline (3434.678 us; speedup 1.0000x reference)
//
#include <hip/hip_runtime.h>
#include <cstdint>
#include <cstddef>

// Problem constants (from setup_inputs): B=4, C=256, H=60, W=80, N=4800
#define BQ 4
#define CDIM 256
#define HH 60
#define WW 80
#define NP 4800
#define NPAD 4864          // padded to 38*128 for tiling
#define TJ 128             // query tile
#define TT 128             // target tile
#define KT 16              // K sub-tile
#define NKT 16             // CDIM / KT
#define NTILES 38          // NPAD / TT
#define TSPLIT 10          // t-chunks per (b, j-tile)
#define NITEMS (BQ * NTILES * TSPLIT)  // 1520

// ---------------- ws layout (bytes) ----------------
// refN : 4*4864*256*4 = 19,922,944
// tarN : 19,922,944
// desT : 2*4*4800*256*4 = 39,321,600
// part : 4*4800*10*16 = 3,072,000
// nn/inc/loss/rec : 4*76,800
#define WS_REFN 0
#define WS_TARN 19922944
#define WS_DEST 39845888
#define WS_PART 79167488
#define WS_NN   82239488
#define WS_INC  82316288
#define WS_LOSS 82393088
#define WS_REC  82469888
// total ~82.5 MB

// ---------------- transpose des (C, HW) -> (HW, C) ----------------
__global__ __launch_bounds__(256)
void k_transpose(const float* __restrict__ src, const float* __restrict__ tgt,
                 float* __restrict__ desT) {
  __shared__ float tile[32][33];
  const int z = blockIdx.z;  // tensor*4 + b
  const float* in = ((z >> 2) ? tgt : src) + (size_t)(z & 3) * CDIM * NP;
  float* out = desT + (size_t)z * NP * CDIM;
  const int hw0 = blockIdx.x * 32;
  const int c0 = blockIdx.y * 32;
  const int tx = threadIdx.x, ty = threadIdx.y;
#pragma unroll
  for (int q = 0; q < 4; ++q)
    tile[ty + q * 8][tx] = in[(size_t)(c0 + ty + q * 8) * NP + hw0 + tx];
  __syncthreads();
#pragma unroll
  for (int q = 0; q < 4; ++q)
    out[(size_t)(hw0 + ty + q * 8) * CDIM + c0 + tx] = tile[tx][ty + q * 8];
}

// ---------------- bilinear sample + L2 normalize ----------------
__global__ __launch_bounds__(256)
void k_sample(const float* __restrict__ desT,
              const float* __restrict__ spts, const float* __restrict__ tpts,
              float* __restrict__ refN, float* __restrict__ tarN) {
  const int n = blockIdx.x;       // 0..NPAD-1
  const int b = blockIdx.y;
  const int tensor = blockIdx.z;  // 0: ref (source), 1: tar (target)
  const int c = threadIdx.x;
  float* outRow = (tensor ? tarN : refN) + ((size_t)b * NPAD + n) * CDIM;
  if (n >= NP) { outRow[c] = 0.f; return; }  // zero pad rows (uniform per block)
  const float* pts = (tensor ? tpts : spts) + ((size_t)b * NP + n) * 2;
  const float gx = pts[0], gy = pts[1];
  const float x = (gx + 1.f) * ((WW - 1) * 0.5f);
  const float y = (gy + 1.f) * ((HH - 1) * 0.5f);
  float x0f = fminf(fmaxf(floorf(x), 0.f), (float)(WW - 1));
  float y0f = fminf(fmaxf(floorf(y), 0.f), (float)(HH - 1));
  float x1f = fminf(x0f + 1.f, (float)(WW - 1));
  float y1f = fminf(y0f + 1.f, (float)(HH - 1));
  const float wx = x - x0f, wy = y - y0f;
  const int ix0 = (int)x0f, ix1 = (int)x1f, iy0 = (int)y0f, iy1 = (int)y1f;
  const float* base = desT + (size_t)(tensor * 4 + b) * NP * CDIM;
  const float v00 = base[((size_t)(iy0 * WW + ix0)) * CDIM + c];
  const float v01 = base[((size_t)(iy0 * WW + ix1)) * CDIM + c];
  const float v10 = base[((size_t)(iy1 * WW + ix0)) * CDIM + c];
  const float v11 = base[((size_t)(iy1 * WW + ix1)) * CDIM + c];
  const float v = v00 * (1.f - wx) * (1.f - wy) + v01 * wx * (1.f - wy)
                + v10 * (1.f - wx) * wy + v11 * wx * wy;
  float s = v + 1e-8f;
  s = s * s;
  float sum = s;
#pragma unroll
  for (int off = 32; off > 0; off >>= 1) sum += __shfl_down(sum, off);
  __shared__ float red[4];
  if ((threadIdx.x & 63) == 0) red[threadIdx.x >> 6] = sum;
  __syncthreads();
  const float total = red[0] + red[1] + red[2] + red[3];
  const float denom = sqrtf(total) + 1e-8f;
  outRow[c] = v / denom;
}

// ---------------- fused dot-product GEMM + dual argmax ----------------
union DotSmem {
  struct { float refS[2][KT][TJ]; float tarS[2][KT][TT]; } s;  // 32 KB
  float4 red[16][TJ];                                          // 32 KB
};

__global__ __launch_bounds__(256, 2)
void k_dot_argmax(const float* __restrict__ refN, const float* __restrict__ tarN,
                  const float* __restrict__ un, const int* __restrict__ relax,
                  float4* __restrict__ partial) {
  __shared__ DotSmem smem;
  const int tid = threadIdx.x;
  const int tj = tid & 15;    // j-group: 16 groups x 8 j = 128
  const int ttg = tid >> 4;   // t-group: 16 groups x 8 t = 128
  const int srow = tid >> 1;  // staging row 0..127
  const int shalf = tid & 1;  // staging half (8 floats each)
  const float rf = (float)relax[0];

  for (int item = blockIdx.x; item < NITEMS; item += gridDim.x) {
    const int b = item / (NTILES * TSPLIT);
    const int r = item - b * (NTILES * TSPLIT);
    const int jt = r / TSPLIT;
    const int tc = r - jt * TSPLIT;
    const int jbase = jt * TJ;
    const int tile0 = (tc * NTILES) / TSPLIT;
    const int tile1 = ((tc + 1) * NTILES) / TSPLIT;
    const float* unb = un + (size_t)b * 2 * NP;

    float jx[8], jy[8];
#pragma unroll
    for (int f = 0; f < 8; ++f) {
      const int j = jbase + tj * 8 + f;
      const int jc = j < NP ? j : NP - 1;
      jx[f] = unb[jc];
      jy[f] = unb[NP + jc];
    }
    float vA[8], vI[8];
    int iA[8], iI[8];
#pragma unroll
    for (int f = 0; f < 8; ++f) { vA[f] = -2.f; vI[f] = -2.f; iA[f] = 0; iI[f] = 0; }

    const float* refBase = refN + ((size_t)b * NPAD + jbase + srow) * CDIM + shalf * 8;

    for (int tile = tile0; tile < tile1; ++tile) {
      const int tbase = tile * TT;
      const float* tarBase = tarN + ((size_t)b * NPAD + tbase + srow) * CDIM + shalf * 8;

      float acc[8][8];
#pragma unroll
      for (int f = 0; f < 8; ++f)
#pragma unroll
        for (int e = 0; e < 8; ++e) acc[f][e] = 0.f;

      // prologue: stage kt=0 into buf 0 (transposed to [k][point])
      {
        const float4 ra0 = *(const float4*)(refBase + 0);
        const float4 ra1 = *(const float4*)(refBase + 4);
        const float4 tb0 = *(const float4*)(tarBase + 0);
        const float4 tb1 = *(const float4*)(tarBase + 4);
        float* rd = &smem.s.refS[0][shalf * 8][srow];
        rd[0 * TJ] = ra0.x; rd[1 * TJ] = ra0.y; rd[2 * TJ] = ra0.z; rd[3 * TJ] = ra0.w;
        rd[4 * TJ] = ra1.x; rd[5 * TJ] = ra1.y; rd[6 * TJ] = ra1.z; rd[7 * TJ] = ra1.w;
        float* td = &smem.s.tarS[0][shalf * 8][srow];
        td[0 * TT] = tb0.x; td[1 * TT] = tb0.y; td[2 * TT] = tb0.z; td[3 * TT] = tb0.w;
        td[4 * TT] = tb1.x; td[5 * TT] = tb1.y; td[6 * TT] = tb1.z; td[7 * TT] = tb1.w;
      }
      __syncthreads();
      int buf = 0;
      for (int kt = 0; kt < NKT; ++kt) {
        float4 ra0, ra1, tb0, tb1;
        const bool pre = (kt + 1 < NKT);
        if (pre) {  // issue next-k-tile loads early (hide under FMA burst)
          const float* rp = refBase + (kt + 1) * KT;
          const float* tp = tarBase + (kt + 1) * KT;
          ra0 = *(const float4*)rp;       ra1 = *(const float4*)(rp + 4);
          tb0 = *(const float4*)tp;       tb1 = *(const float4*)(tp + 4);
        }
        {
          const float* rS = &smem.s.refS[buf][0][0] + tj * 8;
          const float* tS = &smem.s.tarS[buf][0][0] + ttg * 8;
#pragma unroll
          for (int kk = 0; kk < KT; ++kk) {
            const float4 a0 = *(const float4*)(rS + kk * TJ);
            const float4 a1 = *(const float4*)(rS + kk * TJ + 4);
            const float4 b0 = *(const float4*)(tS + kk * TT);
            const float4 b1 = *(const float4*)(tS + kk * TT + 4);
            const float af[8] = {a0.x, a0.y, a0.z, a0.w, a1.x, a1.y, a1.z, a1.w};
            const float bf[8] = {b0.x, b0.y, b0.z, b0.w, b1.x, b1.y, b1.z, b1.w};
#pragma unroll
            for (int f = 0; f < 8; ++f)
#pragma unroll
              for (int e = 0; e < 8; ++e)
                acc[f][e] = fmaf(af[f], bf[e], acc[f][e]);
          }
        }
        if (pre) {  // write-late into the other buffer
          float* rd = &smem.s.refS[buf ^ 1][shalf * 8][srow];
          rd[0 * TJ] = ra0.x; rd[1 * TJ] = ra0.y; rd[2 * TJ] = ra0.z; rd[3 * TJ] = ra0.w;
          rd[4 * TJ] = ra1.x; rd[5 * TJ] = ra1.y; rd[6 * TJ] = ra1.z; rd[7 * TJ] = ra1.w;
          float* td = &smem.s.tarS[buf ^ 1][shalf * 8][srow];
          td[0 * TT] = tb0.x; td[1 * TT] = tb0.y; td[2 * TT] = tb0.z; td[3 * TT] = tb0.w;
          td[4 * TT] = tb1.x; td[5 * TT] = tb1.y; td[6 * TT] = tb1.z; td[7 * TT] = tb1.w;
        }
        __syncthreads();
        buf ^= 1;
      }

      // epilogue: clip + dual running argmax (tie -> smaller index, matches stable argsort)
      float tx[8], ty[8];
#pragma unroll
      for (int e = 0; e < 8; ++e) {
        const int t = tbase + ttg * 8 + e;
        const int tcl = t < NP ? t : NP - 1;
        tx[e] = unb[tcl];
        ty[e] = unb[NP + tcl];
      }
#pragma unroll
      for (int e = 0; e < 8; ++e) {
        const int t = tbase + ttg * 8 + e;
        const bool valid = (t < NP);
#pragma unroll
        for (int f = 0; f < 8; ++f) {
          const float v = fminf(fmaxf(acc[f][e], -1.f), 1.f);
          const bool correct = (fabsf(tx[e] - jx[f]) <= rf) && (fabsf(ty[e] - jy[f]) <= rf);
          if (valid) {
            if (v > vA[f] || (v == vA[f] && t < iA[f])) { vA[f] = v; iA[f] = t; }
            if (!correct && (v > vI[f] || (v == vI[f] && t < iI[f]))) { vI[f] = v; iI[f] = t; }
          }
        }
      }
    }  // tiles in chunk

    // cross-thread reduce over the 16 t-groups sharing each j
    // (k-loop ended with __syncthreads: all smem.s reads are done -> safe to alias red)
#pragma unroll
    for (int f = 0; f < 8; ++f)
      smem.red[ttg][tj * 8 + f] = make_float4(vA[f], (float)iA[f], vI[f], (float)iI[f]);
    __syncthreads();
    if (tid < TJ) {
      const int jglob = jbase + tid;
      if (jglob < NP) {
        float4 best = smem.red[0][tid];
#pragma unroll
        for (int g = 1; g < 16; ++g) {
          const float4 c = smem.red[g][tid];
          if (c.x > best.x || (c.x == best.x && c.y < best.y)) { best.x = c.x; best.y = c.y; }
          if (c.z > best.z || (c.z == best.z && c.w < best.w)) { best.z = c.z; best.w = c.w; }
        }
        partial[((size_t)b * NP + jglob) * TSPLIT + tc] = best;
      }
    }
    __syncthreads();  // before next item re-stages smem.s
  }
}

// ---------------- combine partials -> nn / neg indices ----------------
__global__ __launch_bounds__(256)
void k_combine(const float4* __restrict__ partial, int* __restrict__ nn_idx,
               int* __restrict__ inc_idx) {
  const int gid = blockIdx.x * 256 + threadIdx.x;
  if (gid >= BQ * NP) return;
  float4 best = partial[(size_t)gid * TSPLIT];
#pragma unroll
  for (int tc = 1; tc < TSPLIT; ++tc) {
    const float4 c = partial[(size_t)gid * TSPLIT + tc];
    if (c.x > best.x || (c.x == best.x && c.y < best.y)) { best.x = c.x; best.y = c.y; }
    if (c.z > best.z || (c.z == best.z && c.w < best.w)) { best.z = c.z; best.w = c.w; }
  }
  nn_idx[gid] = (int)best.y;
  inc_idx[gid] = (int)best.w;
}

// ---------------- per-point loss + recall ----------------
__global__ __launch_bounds__(256)
void k_loss(const float* __restrict__ refN, const float* __restrict__ tarN,
            const float* __restrict__ un, const int* __restrict__ nn_idx,
            const int* __restrict__ inc_idx, float* __restrict__ loss_arr,
            float* __restrict__ rec_arr) {
  const int w = threadIdx.x >> 6, lane = threadIdx.x & 63;
  const int n = blockIdx.x * 4 + w;
  const int b = blockIdx.y;
  const int bn = b * NP + n;
  const int neg = inc_idx[bn];
  const float4 rv = *(const float4*)(refN + ((size_t)b * NPAD + n) * CDIM + lane * 4);
  const float4 tv = *(const float4*)(tarN + ((size_t)b * NPAD + n) * CDIM + lane * 4);
  const float4 gv = *(const float4*)(tarN + ((size_t)b * NPAD + neg) * CDIM + lane * 4);
  float dp = 0.f, dn = 0.f, d;
  d = rv.x - tv.x + 1e-6f; dp += d * d;
  d = rv.y - tv.y + 1e-6f; dp += d * d;
  d = rv.z - tv.z + 1e-6f; dp += d * d;
  d = rv.w - tv.w + 1e-6f; dp += d * d;
  d = rv.x - gv.x + 1e-6f; dn += d * d;
  d = rv.y - gv.y + 1e-6f; dn += d * d;
  d = rv.z - gv.z + 1e-6f; dn += d * d;
  d = rv.w - gv.w + 1e-6f; dn += d * d;
#pragma unroll
  for (int off = 32; off > 0; off >>= 1) {
    dp += __shfl_down(dp, off);
    dn += __shfl_down(dn, off);
  }
  if (lane == 0) {
    const float loss = fmaxf(sqrtf(dp) - sqrtf(dn) + 0.2f, 0.f);
    const float* unb = un + (size_t)b * 2 * NP;
    const int nn = nn_idx[bn];
    const float rec = (unb[nn] == unb[n] && unb[NP + nn] == unb[NP + n]) ? 1.f : 0.f;
    loss_arr[bn] = loss;
    rec_arr[bn] = rec;
  }
}

// ---------------- final deterministic reduce ----------------
__global__ __launch_bounds__(256)
void k_finalize(const float* __restrict__ loss_arr, const float* __restrict__ rec_arr,
                float* __restrict__ out) {
  __shared__ float l[256], rr[256];
  float ls = 0.f, rs = 0.f;
  for (int i = threadIdx.x; i < BQ * NP; i += 256) { ls += loss_arr[i]; rs += rec_arr[i]; }
  l[threadIdx.x] = ls;
  rr[threadIdx.x] = rs;
  __syncthreads();
  for (int s = 128; s > 0; s >>= 1) {
    if (threadIdx.x < s) { l[threadIdx.x] += l[threadIdx.x + s]; rr[threadIdx.x] += rr[threadIdx.x + s]; }
    __syncthreads();
  }
  if (threadIdx.x == 0) {
    out[0] = l[0] / (float)(BQ * NP);
    out[1] = rr[0] / (float)(BQ * NP);
  }
}

extern "C" void kernel_launch(void* const* d_in, const int* in_sizes, int n_in,
                              void* d_out, int out_size, void* d_ws, size_t ws_size,
                              hipStream_t stream) {
  const float* src  = (const float*)d_in[0];   // (4,256,60,80)
  const float* tgt  = (const float*)d_in[1];   // (4,256,60,80)
  const float* spts = (const float*)d_in[2];   // (4,60,80,2)
  const float* tpts = (const float*)d_in[3];   // (4,60,80,2)
  const float* un   = (const float*)d_in[4];   // (4,2,60,80)
  const int* relax  = (const int*)d_in[5];     // scalar int

  char* ws = (char*)d_ws;
  float*  refN     = (float*)(ws + WS_REFN);
  float*  tarN     = (float*)(ws + WS_TARN);
  float*  desT     = (float*)(ws + WS_DEST);
  float4* partial  = (float4*)(ws + WS_PART);
  int*    nn_idx   = (int*)(ws + WS_NN);
  int*    inc_idx  = (int*)(ws + WS_INC);
  float*  loss_arr = (float*)(ws + WS_LOSS);
  float*  rec_arr  = (float*)(ws + WS_REC);
  float*  out      = (float*)d_out;

  k_transpose<<<dim3(NP / 32, CDIM / 32, 8), dim3(32, 8), 0, stream>>>(src, tgt, desT);
  k_sample<<<dim3(NPAD, BQ, 2), 256, 0, stream>>>(desT, spts, tpts, refN, tarN);
  k_dot_argmax<<<512, 256, 0, stream>>>(refN, tarN, un, relax, partial);
  k_combine<<<(BQ * NP + 255) / 256, 256, 0, stream>>>(partial, nn_idx, inc_idx);
  k_loss<<<dim3(NP / 4, BQ), 256, 0, stream>>>(refN, tarN, un, nn_idx, inc_idx, loss_arr, rec_arr);
  k_finalize<<<1, 256, 0, stream>>>(loss_arr, rec_arr, out);
}

// Round 2
// 250.690 us; speedup vs baseline: 13.7009x; 13.7009x over previous
//
#include <hip/hip_runtime.h>
#include <cstdint>
#include <cstddef>

// Problem constants: B=4, C=256, H=60, W=80, N=4800
#define BQ 4
#define CDIM 256
#define HH 60
#define WW 80
#define NP 4800
#define NPAD 4864          // 38*128
#define NT 38              // tiles per dim (128-wide)
#define NBLK (BQ * NT * NT)  // 5776 (divisible by 8 -> clean XCD swizzle)

typedef __bf16 bf16x8 __attribute__((ext_vector_type(8)));
typedef float f32x4 __attribute__((ext_vector_type(4)));

// ---------------- ws layout (bytes) ----------------
#define WS_REFN 0              // f32 4*4864*256*4 = 19,922,944
#define WS_TARN 19922944       // f32                19,922,944
#define WS_REFB 39845888       // bf16 4*4864*256*2 = 9,961,472
#define WS_TARB 49807360       // bf16                9,961,472
#define WS_DEST 59768832       // f32 2*4*4800*256*4 = 39,321,600 (dead after k_sample)
#define WS_PART 59768832       // ulonglong2 4*4800*38*16 = 11,673,600 (aliases desT)
#define WS_NN   71442432
#define WS_INC  71519232
#define WS_LOSS 71596032
#define WS_REC  71672832
// total = 99,090,432 bytes

#define GLD16(dst, src) __builtin_amdgcn_global_load_lds( \
    (const __attribute__((address_space(1))) void*)(src), \
    (__attribute__((address_space(3))) void*)(dst), 16, 0, 0)

__device__ inline unsigned short f2bf(float f) {
  unsigned int u = __float_as_uint(f);
  return (unsigned short)((u + 0x7FFFu + ((u >> 16) & 1u)) >> 16);  // RNE
}

// ---------------- transpose des (C, HW) -> (HW, C) ----------------
__global__ __launch_bounds__(256)
void k_transpose(const float* __restrict__ src, const float* __restrict__ tgt,
                 float* __restrict__ desT) {
  __shared__ float tile[32][33];
  const int z = blockIdx.z;  // tensor*4 + b
  const float* in = ((z >> 2) ? tgt : src) + (size_t)(z & 3) * CDIM * NP;
  float* out = desT + (size_t)z * NP * CDIM;
  const int hw0 = blockIdx.x * 32;
  const int c0 = blockIdx.y * 32;
  const int tx = threadIdx.x, ty = threadIdx.y;
#pragma unroll
  for (int q = 0; q < 4; ++q)
    tile[ty + q * 8][tx] = in[(size_t)(c0 + ty + q * 8) * NP + hw0 + tx];
  __syncthreads();
#pragma unroll
  for (int q = 0; q < 4; ++q)
    out[(size_t)(hw0 + ty + q * 8) * CDIM + c0 + tx] = tile[tx][ty + q * 8];
}

// ---------------- bilinear sample + L2 normalize (f32 + bf16 out) ----------------
__global__ __launch_bounds__(256)
void k_sample(const float* __restrict__ desT,
              const float* __restrict__ spts, const float* __restrict__ tpts,
              float* __restrict__ refN, float* __restrict__ tarN,
              unsigned short* __restrict__ refB, unsigned short* __restrict__ tarB) {
  const int n = blockIdx.x;       // 0..NPAD-1
  const int b = blockIdx.y;
  const int tensor = blockIdx.z;  // 0: ref, 1: tar
  const int c = threadIdx.x;
  float* outRow = (tensor ? tarN : refN) + ((size_t)b * NPAD + n) * CDIM;
  unsigned short* outRowB = (tensor ? tarB : refB) + ((size_t)b * NPAD + n) * CDIM;
  if (n >= NP) { outRow[c] = 0.f; outRowB[c] = 0; return; }
  const float* pts = (tensor ? tpts : spts) + ((size_t)b * NP + n) * 2;
  const float gx = pts[0], gy = pts[1];
  const float x = (gx + 1.f) * ((WW - 1) * 0.5f);
  const float y = (gy + 1.f) * ((HH - 1) * 0.5f);
  float x0f = fminf(fmaxf(floorf(x), 0.f), (float)(WW - 1));
  float y0f = fminf(fmaxf(floorf(y), 0.f), (float)(HH - 1));
  float x1f = fminf(x0f + 1.f, (float)(WW - 1));
  float y1f = fminf(y0f + 1.f, (float)(HH - 1));
  const float wx = x - x0f, wy = y - y0f;
  const int ix0 = (int)x0f, ix1 = (int)x1f, iy0 = (int)y0f, iy1 = (int)y1f;
  const float* base = desT + (size_t)(tensor * 4 + b) * NP * CDIM;
  const float v00 = base[((size_t)(iy0 * WW + ix0)) * CDIM + c];
  const float v01 = base[((size_t)(iy0 * WW + ix1)) * CDIM + c];
  const float v10 = base[((size_t)(iy1 * WW + ix0)) * CDIM + c];
  const float v11 = base[((size_t)(iy1 * WW + ix1)) * CDIM + c];
  const float v = v00 * (1.f - wx) * (1.f - wy) + v01 * wx * (1.f - wy)
                + v10 * (1.f - wx) * wy + v11 * wx * wy;
  float s = v + 1e-8f;
  s = s * s;
  float sum = s;
#pragma unroll
  for (int off = 32; off > 0; off >>= 1) sum += __shfl_down(sum, off);
  __shared__ float red[4];
  if ((threadIdx.x & 63) == 0) red[threadIdx.x >> 6] = sum;
  __syncthreads();
  const float total = red[0] + red[1] + red[2] + red[3];
  const float denom = sqrtf(total) + 1e-8f;
  const float o = v / denom;
  outRow[c] = o;
  outRowB[c] = f2bf(o);
}

// ---------------- MFMA GEMM tile + fused dual argmax ----------------
union Smem {
  struct { char A[16384]; char Bm[16384]; } s;  // [128 rows][128 B] each, XOR-swizzled slots
  struct { unsigned long long redA[2][128]; unsigned long long redI[2][128]; } r;
};

__global__ __launch_bounds__(256, 2)
void k_mfma_argmax(const unsigned short* __restrict__ refB,
                   const unsigned short* __restrict__ tarB,
                   const float* __restrict__ un, const int* __restrict__ relax,
                   ulonglong2* __restrict__ partial) {
  __shared__ Smem sm;
  const int tid = threadIdx.x;
  const int lane = tid & 63;
  const int wid = tid >> 6;

  // XCD-bijective swizzle: 5776 = 8 * 722
  const int bid = blockIdx.x;
  const int item = (bid & 7) * (NBLK / 8) + (bid >> 3);
  const int b = item / (NT * NT);
  const int r2 = item - b * NT * NT;
  const int jt = r2 / NT, tt = r2 % NT;
  const int jbase = jt * 128, tbase = tt * 128;

  // staging setup: waves 0,1 stage A(ref rows jbase..+127); waves 2,3 stage B(tar rows tbase..+127)
  const int opB = wid >> 1;
  const int half = wid & 1;
  const unsigned short* gbase =
      (opB ? tarB + ((size_t)b * NPAD + tbase) * CDIM
           : refB + ((size_t)b * NPAD + jbase) * CDIM);
  // rows are 512 B; source chunk pre-swizzled so linear LDS + swizzled read is conflict-free
  const char* gl = (const char*)gbase + (size_t)(half * 64 + (lane >> 3)) * 512
                 + (((lane & 7) ^ ((lane >> 3) & 7)) << 4);
  char* lbase = (opB ? sm.s.Bm : sm.s.A) + half * 8192;

  const int wr = wid >> 1, wc = wid & 1;
  f32x4 acc[4][4];
#pragma unroll
  for (int fj = 0; fj < 4; ++fj)
#pragma unroll
    for (int ft = 0; ft < 4; ++ft) acc[fj][ft] = (f32x4){0.f, 0.f, 0.f, 0.f};

  for (int kb = 0; kb < 4; ++kb) {   // BK = 64, K = 256
    const char* g = gl + kb * 128;
#pragma unroll
    for (int q = 0; q < 8; ++q)
      GLD16(lbase + q * 1024, g + q * 4096);
    __syncthreads();
#pragma unroll
    for (int ks = 0; ks < 2; ++ks) {
      const int slotoff = (((ks * 4 + (lane >> 4)) ^ (lane & 7)) << 4);
      bf16x8 af[4], bg[4];
#pragma unroll
      for (int f = 0; f < 4; ++f) {
        af[f] = *(const bf16x8*)(sm.s.A  + (wr * 64 + f * 16 + (lane & 15)) * 128 + slotoff);
        bg[f] = *(const bf16x8*)(sm.s.Bm + (wc * 64 + f * 16 + (lane & 15)) * 128 + slotoff);
      }
#pragma unroll
      for (int fj = 0; fj < 4; ++fj)
#pragma unroll
        for (int ft = 0; ft < 4; ++ft)
          acc[fj][ft] = __builtin_amdgcn_mfma_f32_16x16x32_bf16(af[fj], bg[ft], acc[fj][ft], 0, 0, 0);
    }
    __syncthreads();
  }

  // ---- epilogue: dual argmax with packed u64 keys ----
  const float rf = (float)relax[0];
  const float* unb = un + (size_t)b * 2 * NP;
  const int tcol = tbase + wc * 64 + (lane & 15);
  float tx[4], ty[4];
#pragma unroll
  for (int ft = 0; ft < 4; ++ft) {
    const int t = tcol + ft * 16;
    const int c = t < NP ? t : NP - 1;
    tx[ft] = unb[c];
    ty[ft] = unb[NP + c];
  }
#pragma unroll
  for (int fj = 0; fj < 4; ++fj)
#pragma unroll
    for (int i = 0; i < 4; ++i) {
      const int j = jbase + wr * 64 + fj * 16 + (lane >> 4) * 4 + i;
      const int jc = j < NP ? j : NP - 1;
      const float jx = unb[jc], jy = unb[NP + jc];
      unsigned long long kA = 0ull, kI = 0ull;
#pragma unroll
      for (int ft = 0; ft < 4; ++ft) {
        const float v = fminf(fmaxf(acc[fj][ft][i], -1.f), 1.f);
        const unsigned int vb = __float_as_uint(v + 2.0f);  // monotone bits, v+2 in [1,3]
        const unsigned long long key =
            ((unsigned long long)vb << 32) | (unsigned int)(8192 - (tcol + ft * 16));
        if (key > kA) kA = key;
        const bool corr = (fabsf(tx[ft] - jx) <= rf) && (fabsf(ty[ft] - jy) <= rf);
        if (!corr && key > kI) kI = key;
      }
#pragma unroll
      for (int d = 1; d < 16; d <<= 1) {
        const unsigned long long oA = __shfl_xor(kA, d);
        const unsigned long long oI = __shfl_xor(kI, d);
        if (oA > kA) kA = oA;
        if (oI > kI) kI = oI;
      }
      if ((lane & 15) == 0) {
        const int jl = wr * 64 + fj * 16 + (lane >> 4) * 4 + i;
        sm.r.redA[wc][jl] = kA;
        sm.r.redI[wc][jl] = kI;
      }
    }
  __syncthreads();
  if (tid < 128) {
    const int jg = jbase + tid;
    if (jg < NP) {
      unsigned long long kA = sm.r.redA[0][tid], kI = sm.r.redI[0][tid];
      if (sm.r.redA[1][tid] > kA) kA = sm.r.redA[1][tid];
      if (sm.r.redI[1][tid] > kI) kI = sm.r.redI[1][tid];
      partial[((size_t)b * NP + jg) * NT + tt] = make_ulonglong2(kA, kI);
    }
  }
}

// ---------------- combine partials -> nn / neg indices ----------------
__global__ __launch_bounds__(256)
void k_combine(const ulonglong2* __restrict__ partial, int* __restrict__ nn_idx,
               int* __restrict__ inc_idx) {
  const int gid = blockIdx.x * 256 + threadIdx.x;
  if (gid >= BQ * NP) return;
  unsigned long long kA = 0ull, kI = 0ull;
#pragma unroll
  for (int tt = 0; tt < NT; ++tt) {
    const ulonglong2 p = partial[(size_t)gid * NT + tt];
    if (p.x > kA) kA = p.x;
    if (p.y > kI) kI = p.y;
  }
  nn_idx[gid] = 8192 - (int)(kA & 0xFFFFFFFFull);
  inc_idx[gid] = 8192 - (int)(kI & 0xFFFFFFFFull);
}

// ---------------- per-point loss + recall (f32 vectors) ----------------
__global__ __launch_bounds__(256)
void k_loss(const float* __restrict__ refN, const float* __restrict__ tarN,
            const float* __restrict__ un, const int* __restrict__ nn_idx,
            const int* __restrict__ inc_idx, float* __restrict__ loss_arr,
            float* __restrict__ rec_arr) {
  const int w = threadIdx.x >> 6, lane = threadIdx.x & 63;
  const int n = blockIdx.x * 4 + w;
  const int b = blockIdx.y;
  const int bn = b * NP + n;
  const int neg = inc_idx[bn];
  const float4 rv = *(const float4*)(refN + ((size_t)b * NPAD + n) * CDIM + lane * 4);
  const float4 tv = *(const float4*)(tarN + ((size_t)b * NPAD + n) * CDIM + lane * 4);
  const float4 gv = *(const float4*)(tarN + ((size_t)b * NPAD + neg) * CDIM + lane * 4);
  float dp = 0.f, dn = 0.f, d;
  d = rv.x - tv.x + 1e-6f; dp += d * d;
  d = rv.y - tv.y + 1e-6f; dp += d * d;
  d = rv.z - tv.z + 1e-6f; dp += d * d;
  d = rv.w - tv.w + 1e-6f; dp += d * d;
  d = rv.x - gv.x + 1e-6f; dn += d * d;
  d = rv.y - gv.y + 1e-6f; dn += d * d;
  d = rv.z - gv.z + 1e-6f; dn += d * d;
  d = rv.w - gv.w + 1e-6f; dn += d * d;
#pragma unroll
  for (int off = 32; off > 0; off >>= 1) {
    dp += __shfl_down(dp, off);
    dn += __shfl_down(dn, off);
  }
  if (lane == 0) {
    const float loss = fmaxf(sqrtf(dp) - sqrtf(dn) + 0.2f, 0.f);
    const float* unb = un + (size_t)b * 2 * NP;
    const int nn = nn_idx[bn];
    const float rec = (unb[nn] == unb[n] && unb[NP + nn] == unb[NP + n]) ? 1.f : 0.f;
    loss_arr[bn] = loss;
    rec_arr[bn] = rec;
  }
}

// ---------------- final deterministic reduce ----------------
__global__ __launch_bounds__(256)
void k_finalize(const float* __restrict__ loss_arr, const float* __restrict__ rec_arr,
                float* __restrict__ out) {
  __shared__ float l[256], rr[256];
  float ls = 0.f, rs = 0.f;
  for (int i = threadIdx.x; i < BQ * NP; i += 256) { ls += loss_arr[i]; rs += rec_arr[i]; }
  l[threadIdx.x] = ls;
  rr[threadIdx.x] = rs;
  __syncthreads();
  for (int s = 128; s > 0; s >>= 1) {
    if (threadIdx.x < s) { l[threadIdx.x] += l[threadIdx.x + s]; rr[threadIdx.x] += rr[threadIdx.x + s]; }
    __syncthreads();
  }
  if (threadIdx.x == 0) {
    out[0] = l[0] / (float)(BQ * NP);
    out[1] = rr[0] / (float)(BQ * NP);
  }
}

extern "C" void kernel_launch(void* const* d_in, const int* in_sizes, int n_in,
                              void* d_out, int out_size, void* d_ws, size_t ws_size,
                              hipStream_t stream) {
  const float* src  = (const float*)d_in[0];
  const float* tgt  = (const float*)d_in[1];
  const float* spts = (const float*)d_in[2];
  const float* tpts = (const float*)d_in[3];
  const float* un   = (const float*)d_in[4];
  const int* relax  = (const int*)d_in[5];

  char* ws = (char*)d_ws;
  float*          refN     = (float*)(ws + WS_REFN);
  float*          tarN     = (float*)(ws + WS_TARN);
  unsigned short* refB     = (unsigned short*)(ws + WS_REFB);
  unsigned short* tarB     = (unsigned short*)(ws + WS_TARB);
  float*          desT     = (float*)(ws + WS_DEST);
  ulonglong2*     partial  = (ulonglong2*)(ws + WS_PART);
  int*            nn_idx   = (int*)(ws + WS_NN);
  int*            inc_idx  = (int*)(ws + WS_INC);
  float*          loss_arr = (float*)(ws + WS_LOSS);
  float*          rec_arr  = (float*)(ws + WS_REC);
  float*          out      = (float*)d_out;

  k_transpose<<<dim3(NP / 32, CDIM / 32, 8), dim3(32, 8), 0, stream>>>(src, tgt, desT);
  k_sample<<<dim3(NPAD, BQ, 2), 256, 0, stream>>>(desT, spts, tpts, refN, tarN, refB, tarB);
  k_mfma_argmax<<<NBLK, 256, 0, stream>>>(refB, tarB, un, relax, partial);
  k_combine<<<(BQ * NP + 255) / 256, 256, 0, stream>>>(partial, nn_idx, inc_idx);
  k_loss<<<dim3(NP / 4, BQ), 256, 0, stream>>>(refN, tarN, un, nn_idx, inc_idx, loss_arr, rec_arr);
  k_finalize<<<1, 256, 0, stream>>>(loss_arr, rec_arr, out);
}

// Round 3
// 180.758 us; speedup vs baseline: 19.0016x; 1.3869x over previous
//
#include <hip/hip_runtime.h>
#include <cstdint>
#include <cstddef>

// Problem constants: B=4, C=256, H=60, W=80, N=4800
#define BQ 4
#define CDIM 256
#define HH 60
#define WW 80
#define NP 4800
#define NPAD 4864          // 19*256
#define BT 256             // tile in t (rows, A = tar)
#define BJ 256             // tile in j (cols, B = ref)
#define NTT 19
#define NTJ 19
#define NBLK (BQ * NTJ * NTT)   // 1444

typedef __bf16 bf16x8 __attribute__((ext_vector_type(8)));
typedef float f32x4 __attribute__((ext_vector_type(4)));

// ---------------- ws layout (bytes) ----------------
#define WS_REFN 0              // f32 4*4864*256*4 = 19,922,944
#define WS_TARN 19922944       // f32                19,922,944
#define WS_REFB 39845888       // bf16 4*4864*256*2 = 9,961,472
#define WS_TARB 49807360       // bf16                9,961,472
#define WS_DEST 59768832       // f32 2*4*4800*256*4 = 39,321,600 (dead after k_sample)
#define WS_PART 59768832       // ulonglong2 4*4800*19*16 = 5,836,800 (aliases desT)
#define WS_LOSS 65605632       // f32 19200
#define WS_REC  65682432       // f32 19200
// end 65,759,232 — within the 99 MB footprint round 2 ran with

#define GLD16(dst, src) __builtin_amdgcn_global_load_lds( \
    (const __attribute__((address_space(1))) void*)(src), \
    (__attribute__((address_space(3))) void*)(dst), 16, 0, 0)

__device__ inline unsigned short f2bf(float f) {
  unsigned int u = __float_as_uint(f);
  return (unsigned short)((u + 0x7FFFu + ((u >> 16) & 1u)) >> 16);  // RNE
}

// ---------------- transpose des (C, HW) -> (HW, C) ----------------
__global__ __launch_bounds__(256)
void k_transpose(const float* __restrict__ src, const float* __restrict__ tgt,
                 float* __restrict__ desT) {
  __shared__ float tile[32][33];
  const int z = blockIdx.z;  // tensor*4 + b
  const float* in = ((z >> 2) ? tgt : src) + (size_t)(z & 3) * CDIM * NP;
  float* out = desT + (size_t)z * NP * CDIM;
  const int hw0 = blockIdx.x * 32;
  const int c0 = blockIdx.y * 32;
  const int tx = threadIdx.x, ty = threadIdx.y;
#pragma unroll
  for (int q = 0; q < 4; ++q)
    tile[ty + q * 8][tx] = in[(size_t)(c0 + ty + q * 8) * NP + hw0 + tx];
  __syncthreads();
#pragma unroll
  for (int q = 0; q < 4; ++q)
    out[(size_t)(hw0 + ty + q * 8) * CDIM + c0 + tx] = tile[tx][ty + q * 8];
}

// ---------------- bilinear sample + L2 normalize: wave per point ----------------
__global__ __launch_bounds__(256)
void k_sample(const float* __restrict__ desT,
              const float* __restrict__ spts, const float* __restrict__ tpts,
              float* __restrict__ refN, float* __restrict__ tarN,
              unsigned short* __restrict__ refB, unsigned short* __restrict__ tarB) {
  const int w = threadIdx.x >> 6, lane = threadIdx.x & 63;
  const int n = blockIdx.x * 4 + w;         // 0..NPAD-1
  const int b = blockIdx.y;
  const int tensor = blockIdx.z;            // 0: ref, 1: tar
  float* outRow = (tensor ? tarN : refN) + ((size_t)b * NPAD + n) * CDIM;
  unsigned short* outRowB = (tensor ? tarB : refB) + ((size_t)b * NPAD + n) * CDIM;
  if (n >= NP) {  // zero pad rows (uniform per wave)
    *(float4*)(outRow + lane * 4) = make_float4(0.f, 0.f, 0.f, 0.f);
    *(ushort4*)(outRowB + lane * 4) = make_ushort4(0, 0, 0, 0);
    return;
  }
  const float* pts = (tensor ? tpts : spts) + ((size_t)b * NP + n) * 2;
  const float gx = pts[0], gy = pts[1];
  const float x = (gx + 1.f) * ((WW - 1) * 0.5f);
  const float y = (gy + 1.f) * ((HH - 1) * 0.5f);
  float x0f = fminf(fmaxf(floorf(x), 0.f), (float)(WW - 1));
  float y0f = fminf(fmaxf(floorf(y), 0.f), (float)(HH - 1));
  float x1f = fminf(x0f + 1.f, (float)(WW - 1));
  float y1f = fminf(y0f + 1.f, (float)(HH - 1));
  const float wx = x - x0f, wy = y - y0f;
  const int ix0 = (int)x0f, ix1 = (int)x1f, iy0 = (int)y0f, iy1 = (int)y1f;
  const float* base = desT + (size_t)(tensor * 4 + b) * NP * CDIM + lane * 4;
  const float4 v00 = *(const float4*)(base + (size_t)(iy0 * WW + ix0) * CDIM);
  const float4 v01 = *(const float4*)(base + (size_t)(iy0 * WW + ix1) * CDIM);
  const float4 v10 = *(const float4*)(base + (size_t)(iy1 * WW + ix0) * CDIM);
  const float4 v11 = *(const float4*)(base + (size_t)(iy1 * WW + ix1) * CDIM);
  const float w00 = (1.f - wx) * (1.f - wy), w01 = wx * (1.f - wy);
  const float w10 = (1.f - wx) * wy,         w11 = wx * wy;
  float4 v;
  v.x = v00.x * w00 + v01.x * w01 + v10.x * w10 + v11.x * w11;
  v.y = v00.y * w00 + v01.y * w01 + v10.y * w10 + v11.y * w11;
  v.z = v00.z * w00 + v01.z * w01 + v10.z * w10 + v11.z * w11;
  v.w = v00.w * w00 + v01.w * w01 + v10.w * w10 + v11.w * w11;
  float s0 = v.x + 1e-8f, s1 = v.y + 1e-8f, s2 = v.z + 1e-8f, s3 = v.w + 1e-8f;
  float sum = s0 * s0 + s1 * s1 + s2 * s2 + s3 * s3;
#pragma unroll
  for (int d = 1; d < 64; d <<= 1) sum += __shfl_xor(sum, d);
  const float inv = 1.f / (sqrtf(sum) + 1e-8f);
  float4 o;
  o.x = v.x * inv; o.y = v.y * inv; o.z = v.z * inv; o.w = v.w * inv;
  *(float4*)(outRow + lane * 4) = o;
  *(ushort4*)(outRowB + lane * 4) = make_ushort4(f2bf(o.x), f2bf(o.y), f2bf(o.z), f2bf(o.w));
}

// ---------------- MFMA GEMM (A=tar rows t, B=ref cols j) + fused dual argmax ----------------
__global__ __launch_bounds__(512, 2)
void k_mfma_argmax(const unsigned short* __restrict__ tarB,
                   const unsigned short* __restrict__ refB,
                   const float* __restrict__ un, const int* __restrict__ relax,
                   ulonglong2* __restrict__ partial) {
  extern __shared__ char lds[];  // 2 buffers x (A 32KB + B 32KB) = 128 KiB
  const int tid = threadIdx.x;
  const int lane = tid & 63;
  const int wid = tid >> 6;

  // bijective XCD swizzle (1444 % 8 != 0 -> m204 variant)
  const int q8 = NBLK >> 3, r8 = NBLK & 7;   // 180, 4
  const int xcd = blockIdx.x & 7, sub = blockIdx.x >> 3;
  const int item = (xcd < r8 ? xcd * (q8 + 1) : r8 * (q8 + 1) + (xcd - r8) * q8) + sub;
  const int b = item / (NTJ * NTT);
  const int r2 = item - b * (NTJ * NTT);
  const int jt = r2 / NTT, tt = r2 % NTT;
  const int tbase = tt * BT, jbase = jt * BJ;

  // staging: waves 0-3 stage A (tar), waves 4-7 stage B (ref)
  const int grp = wid >> 2;      // 0: A, 1: B
  const int w4 = wid & 3;
  const unsigned short* gsrc = grp ? refB + ((size_t)b * NPAD + jbase) * CDIM
                                   : tarB + ((size_t)b * NPAD + tbase) * CDIM;
  // row = w4*64 + q*8 + (lane>>3); stored slot (lane&7) holds global slot (lane&7)^(row&7)
  const char* gl = (const char*)gsrc + (size_t)(w4 * 64 + (lane >> 3)) * 512
                 + (((lane & 7) ^ ((lane >> 3) & 7)) << 4);
  const int ldsGrp = grp * 32768 + w4 * 8192;  // wave-uniform; HW appends lane*16

#define STAGE(buf, kb) do { \
    char* ldst = lds + (buf) * 65536 + ldsGrp; \
    const char* gsp = gl + (kb) * 128; \
    _Pragma("unroll") for (int qq = 0; qq < 8; ++qq) \
      GLD16(ldst + qq * 1024, gsp + qq * 4096); \
  } while (0)

  const int wr = wid >> 2, wc = wid & 3;  // wave tile: t-half wr (128 rows) x j-quarter wc (64 cols)
  const int l15 = lane & 15, h = lane >> 4;

  f32x4 acc[8][4];
#pragma unroll
  for (int fa = 0; fa < 8; ++fa)
#pragma unroll
    for (int fb = 0; fb < 4; ++fb) acc[fa][fb] = (f32x4){0.f, 0.f, 0.f, 0.f};

  STAGE(0, 0);
  __syncthreads();   // emits vmcnt(0)+lgkmcnt(0) drain + barrier
  for (int kb = 0; kb < 4; ++kb) {   // BK = 64, K = 256
    const int buf = kb & 1;
    if (kb < 3) STAGE(buf ^ 1, kb + 1);   // T3: issue next-tile loads BEFORE compute
    const char* ab = lds + buf * 65536;
    const char* bb = ab + 32768;
#pragma unroll
    for (int ks = 0; ks < 2; ++ks) {
      const int sx = ((ks * 4 + h) ^ (lane & 7)) << 4;
      bf16x8 af[8], bg[4];
#pragma unroll
      for (int fa = 0; fa < 8; ++fa)
        af[fa] = *(const bf16x8*)(ab + (wr * 128 + fa * 16 + l15) * 128 + sx);
#pragma unroll
      for (int fb = 0; fb < 4; ++fb)
        bg[fb] = *(const bf16x8*)(bb + (wc * 64 + fb * 16 + l15) * 128 + sx);
#pragma unroll
      for (int fa = 0; fa < 8; ++fa)
#pragma unroll
        for (int fb = 0; fb < 4; ++fb)
          acc[fa][fb] = __builtin_amdgcn_mfma_f32_16x16x32_bf16(af[fa], bg[fb], acc[fa][fb], 0, 0, 0);
    }
    if (kb < 3) __syncthreads();
  }

  // ---- epilogue: in-lane t-scan (ascending t, strict > => smallest-index tie-break) ----
  const float rf = (float)relax[0];
  const float* unb = un + (size_t)b * 2 * NP;
  const bool lastT = (tt == NTT - 1);
  float jx[4], jy[4];
#pragma unroll
  for (int fb = 0; fb < 4; ++fb) {
    int j = jbase + wc * 64 + fb * 16 + l15;
    if (j >= NP) j = NP - 1;   // padded j cols: results discarded at write
    jx[fb] = unb[j]; jy[fb] = unb[NP + j];
  }
  float vA[4], vI[4];
  int tA[4], tI[4];
#pragma unroll
  for (int fb = 0; fb < 4; ++fb) { vA[fb] = -2.f; vI[fb] = -2.f; tA[fb] = 0; tI[fb] = 0; }
  const int tb0 = tbase + wr * 128 + h * 4;
#pragma unroll
  for (int fa = 0; fa < 8; ++fa) {
#pragma unroll
    for (int i = 0; i < 4; ++i) {
      const int t = tb0 + fa * 16 + i;
      const int tcl = t < NP ? t : NP - 1;
      const float tx = unb[tcl], ty = unb[NP + tcl];   // broadcast within 16-lane group
      const bool okT = (!lastT) || (t < NP);
#pragma unroll
      for (int fb = 0; fb < 4; ++fb) {
        float v = acc[fa][fb][i];
        if (!okT) v = -2.f;   // padded t rows never selected
        const bool corr = (fabsf(tx - jx[fb]) <= rf) && (fabsf(ty - jy[fb]) <= rf);
        if (v > vA[fb]) { vA[fb] = v; tA[fb] = t; }
        if (!corr && v > vI[fb]) { vI[fb] = v; tI[fb] = t; }
      }
    }
  }

  // cross-lane over the 4 h-groups (u64 keys: value bits | (8191 - t))
  ulonglong2* red = (ulonglong2*)lds;   // [2][256]; buf0 region free (last reads were kb=2, barrier'd)
#pragma unroll
  for (int fb = 0; fb < 4; ++fb) {
    unsigned long long kA =
        ((unsigned long long)__float_as_uint(vA[fb] + 2.f) << 32) | (unsigned int)(8191 - tA[fb]);
    unsigned long long kI =
        ((unsigned long long)__float_as_uint(vI[fb] + 2.f) << 32) | (unsigned int)(8191 - tI[fb]);
#pragma unroll
    for (int d = 16; d < 64; d <<= 1) {
      const unsigned long long oA = __shfl_xor(kA, d);
      const unsigned long long oI = __shfl_xor(kI, d);
      if (oA > kA) kA = oA;
      if (oI > kI) kI = oI;
    }
    if (h == 0) red[wr * 256 + wc * 64 + fb * 16 + l15] = make_ulonglong2(kA, kI);
  }
  __syncthreads();
  if (tid < 256) {
    const int jg = jbase + tid;
    if (jg < NP) {
      ulonglong2 p0 = red[tid];
      const ulonglong2 p1 = red[256 + tid];
      if (p1.x > p0.x) p0.x = p1.x;
      if (p1.y > p0.y) p0.y = p1.y;
      partial[((size_t)b * NP + jg) * NTT + tt] = p0;
    }
  }
#undef STAGE
}

// ---------------- fused combine + per-point loss + recall (wave per point) ----------------
__global__ __launch_bounds__(256)
void k_loss(const float* __restrict__ refN, const float* __restrict__ tarN,
            const float* __restrict__ un, const ulonglong2* __restrict__ partial,
            float* __restrict__ loss_arr, float* __restrict__ rec_arr) {
  const int w = threadIdx.x >> 6, lane = threadIdx.x & 63;
  const int n = blockIdx.x * 4 + w;
  const int b = blockIdx.y;
  const int bn = b * NP + n;
  unsigned long long kA = 0ull, kI = 0ull;
  if (lane < NTT) {
    const ulonglong2 p = partial[(size_t)bn * NTT + lane];
    kA = p.x; kI = p.y;
  }
#pragma unroll
  for (int d = 1; d < 64; d <<= 1) {
    const unsigned long long oA = __shfl_xor(kA, d);
    const unsigned long long oI = __shfl_xor(kI, d);
    if (oA > kA) kA = oA;
    if (oI > kI) kI = oI;
  }
  const int nn  = 8191 - (int)(kA & 0xFFFFFFFFull);
  const int neg = 8191 - (int)(kI & 0xFFFFFFFFull);
  const float4 rv = *(const float4*)(refN + ((size_t)b * NPAD + n) * CDIM + lane * 4);
  const float4 tv = *(const float4*)(tarN + ((size_t)b * NPAD + n) * CDIM + lane * 4);
  const float4 gv = *(const float4*)(tarN + ((size_t)b * NPAD + neg) * CDIM + lane * 4);
  float dp = 0.f, dn = 0.f, d;
  d = rv.x - tv.x + 1e-6f; dp += d * d;
  d = rv.y - tv.y + 1e-6f; dp += d * d;
  d = rv.z - tv.z + 1e-6f; dp += d * d;
  d = rv.w - tv.w + 1e-6f; dp += d * d;
  d = rv.x - gv.x + 1e-6f; dn += d * d;
  d = rv.y - gv.y + 1e-6f; dn += d * d;
  d = rv.z - gv.z + 1e-6f; dn += d * d;
  d = rv.w - gv.w + 1e-6f; dn += d * d;
#pragma unroll
  for (int off = 1; off < 64; off <<= 1) {
    dp += __shfl_xor(dp, off);
    dn += __shfl_xor(dn, off);
  }
  if (lane == 0) {
    const float loss = fmaxf(sqrtf(dp) - sqrtf(dn) + 0.2f, 0.f);
    const float* unb = un + (size_t)b * 2 * NP;
    const float rec = (unb[nn] == unb[n] && unb[NP + nn] == unb[NP + n]) ? 1.f : 0.f;
    loss_arr[bn] = loss;
    rec_arr[bn] = rec;
  }
}

// ---------------- final deterministic reduce ----------------
__global__ __launch_bounds__(256)
void k_finalize(const float* __restrict__ loss_arr, const float* __restrict__ rec_arr,
                float* __restrict__ out) {
  __shared__ float l[256], rr[256];
  float ls = 0.f, rs = 0.f;
  for (int i = threadIdx.x; i < BQ * NP; i += 256) { ls += loss_arr[i]; rs += rec_arr[i]; }
  l[threadIdx.x] = ls;
  rr[threadIdx.x] = rs;
  __syncthreads();
  for (int s = 128; s > 0; s >>= 1) {
    if (threadIdx.x < s) { l[threadIdx.x] += l[threadIdx.x + s]; rr[threadIdx.x] += rr[threadIdx.x + s]; }
    __syncthreads();
  }
  if (threadIdx.x == 0) {
    out[0] = l[0] / (float)(BQ * NP);
    out[1] = rr[0] / (float)(BQ * NP);
  }
}

extern "C" void kernel_launch(void* const* d_in, const int* in_sizes, int n_in,
                              void* d_out, int out_size, void* d_ws, size_t ws_size,
                              hipStream_t stream) {
  const float* src  = (const float*)d_in[0];
  const float* tgt  = (const float*)d_in[1];
  const float* spts = (const float*)d_in[2];
  const float* tpts = (const float*)d_in[3];
  const float* un   = (const float*)d_in[4];
  const int* relax  = (const int*)d_in[5];

  char* ws = (char*)d_ws;
  float*          refN     = (float*)(ws + WS_REFN);
  float*          tarN     = (float*)(ws + WS_TARN);
  unsigned short* refB     = (unsigned short*)(ws + WS_REFB);
  unsigned short* tarB     = (unsigned short*)(ws + WS_TARB);
  float*          desT     = (float*)(ws + WS_DEST);
  ulonglong2*     partial  = (ulonglong2*)(ws + WS_PART);
  float*          loss_arr = (float*)(ws + WS_LOSS);
  float*          rec_arr  = (float*)(ws + WS_REC);
  float*          out      = (float*)d_out;

  k_transpose<<<dim3(NP / 32, CDIM / 32, 8), dim3(32, 8), 0, stream>>>(src, tgt, desT);
  k_sample<<<dim3(NPAD / 4, BQ, 2), 256, 0, stream>>>(desT, spts, tpts, refN, tarN, refB, tarB);
  k_mfma_argmax<<<NBLK, 512, 131072, stream>>>(tarB, refB, un, relax, partial);
  k_loss<<<dim3(NP / 4, BQ), 256, 0, stream>>>(refN, tarN, un, partial, loss_arr, rec_arr);
  k_finalize<<<1, 256, 0, stream>>>(loss_arr, rec_arr, out);
}

// Round 4
// 144.408 us; speedup vs baseline: 23.7845x; 1.2517x over previous
//
#include <hip/hip_runtime.h>
#include <cstdint>
#include <cstddef>

// Problem constants: B=4, C=256, H=60, W=80, N=4800
#define BQ 4
#define CDIM 256
#define HH 60
#define WW 80
#define NP 4800
#define NPAD 4864          // lcm pad: 38*128 = 19*256
#define BT 256             // tile rows (t, A = tar)
#define BJ 128             // tile cols (j, B = ref)
#define BK 32              // K sub-tile
#define NTT 19             // t tiles (256)
#define NTJ 38             // j tiles (128)
#define NBLK (BQ * NTJ * NTT)   // 2888, %8==0

typedef __bf16 bf16x8 __attribute__((ext_vector_type(8)));
typedef float f32x4 __attribute__((ext_vector_type(4)));

// ---------------- ws layout (bytes) ----------------
#define WS_DEST 0              // f32 2*4*4800*256*4 = 39,321,600 (dead after k_sample)
#define WS_PART 0              // uint2 4*4800*19*8 = 2,918,400 (aliases desT)
#define WS_REFB 39321600       // bf16 4*4864*256*2 = 9,961,472
#define WS_TARB 49283072       // bf16                9,961,472
#define WS_LOSS 59244544       // f32 19200 = 76,800
#define WS_REC  59321344       // f32 19200
// end 59,398,144 (< the 99 MB footprint earlier rounds ran with)

#define GLD16(dst, src) __builtin_amdgcn_global_load_lds( \
    (const __attribute__((address_space(1))) void*)(src), \
    (__attribute__((address_space(3))) void*)(dst), 16, 0, 0)

__device__ inline unsigned short f2bf(float f) {
  unsigned int u = __float_as_uint(f);
  return (unsigned short)((u + 0x7FFFu + ((u >> 16) & 1u)) >> 16);  // RNE
}
__device__ inline float bf2f(unsigned short s) {
  return __uint_as_float((unsigned int)s << 16);
}

// ---------------- transpose des (C, HW) -> (HW, C) ----------------
__global__ __launch_bounds__(256)
void k_transpose(const float* __restrict__ src, const float* __restrict__ tgt,
                 float* __restrict__ desT) {
  __shared__ float tile[32][33];
  const int z = blockIdx.z;  // tensor*4 + b
  const float* in = ((z >> 2) ? tgt : src) + (size_t)(z & 3) * CDIM * NP;
  float* out = desT + (size_t)z * NP * CDIM;
  const int hw0 = blockIdx.x * 32;
  const int c0 = blockIdx.y * 32;
  const int tx = threadIdx.x, ty = threadIdx.y;
#pragma unroll
  for (int q = 0; q < 4; ++q)
    tile[ty + q * 8][tx] = in[(size_t)(c0 + ty + q * 8) * NP + hw0 + tx];
  __syncthreads();
#pragma unroll
  for (int q = 0; q < 4; ++q)
    out[(size_t)(hw0 + ty + q * 8) * CDIM + c0 + tx] = tile[tx][ty + q * 8];
}

// ---------------- bilinear sample + L2 normalize -> bf16 rows ----------------
__global__ __launch_bounds__(256)
void k_sample(const float* __restrict__ desT,
              const float* __restrict__ spts, const float* __restrict__ tpts,
              unsigned short* __restrict__ refB, unsigned short* __restrict__ tarB) {
  const int w = threadIdx.x >> 6, lane = threadIdx.x & 63;
  const int n = blockIdx.x * 4 + w;         // 0..NPAD-1
  const int b = blockIdx.y;
  const int tensor = blockIdx.z;            // 0: ref, 1: tar
  unsigned short* outRowB = (tensor ? tarB : refB) + ((size_t)b * NPAD + n) * CDIM;
  if (n >= NP) {  // zero pad rows (uniform per wave)
    *(ushort4*)(outRowB + lane * 4) = make_ushort4(0, 0, 0, 0);
    return;
  }
  const float* pts = (tensor ? tpts : spts) + ((size_t)b * NP + n) * 2;
  const float gx = pts[0], gy = pts[1];
  const float x = (gx + 1.f) * ((WW - 1) * 0.5f);
  const float y = (gy + 1.f) * ((HH - 1) * 0.5f);
  float x0f = fminf(fmaxf(floorf(x), 0.f), (float)(WW - 1));
  float y0f = fminf(fmaxf(floorf(y), 0.f), (float)(HH - 1));
  float x1f = fminf(x0f + 1.f, (float)(WW - 1));
  float y1f = fminf(y0f + 1.f, (float)(HH - 1));
  const float wx = x - x0f, wy = y - y0f;
  const int ix0 = (int)x0f, ix1 = (int)x1f, iy0 = (int)y0f, iy1 = (int)y1f;
  const float* base = desT + (size_t)(tensor * 4 + b) * NP * CDIM + lane * 4;
  const float4 v00 = *(const float4*)(base + (size_t)(iy0 * WW + ix0) * CDIM);
  const float4 v01 = *(const float4*)(base + (size_t)(iy0 * WW + ix1) * CDIM);
  const float4 v10 = *(const float4*)(base + (size_t)(iy1 * WW + ix0) * CDIM);
  const float4 v11 = *(const float4*)(base + (size_t)(iy1 * WW + ix1) * CDIM);
  const float w00 = (1.f - wx) * (1.f - wy), w01 = wx * (1.f - wy);
  const float w10 = (1.f - wx) * wy,         w11 = wx * wy;
  float4 v;
  v.x = v00.x * w00 + v01.x * w01 + v10.x * w10 + v11.x * w11;
  v.y = v00.y * w00 + v01.y * w01 + v10.y * w10 + v11.y * w11;
  v.z = v00.z * w00 + v01.z * w01 + v10.z * w10 + v11.z * w11;
  v.w = v00.w * w00 + v01.w * w01 + v10.w * w10 + v11.w * w11;
  float s0 = v.x + 1e-8f, s1 = v.y + 1e-8f, s2 = v.z + 1e-8f, s3 = v.w + 1e-8f;
  float sum = s0 * s0 + s1 * s1 + s2 * s2 + s3 * s3;
#pragma unroll
  for (int d = 1; d < 64; d <<= 1) sum += __shfl_xor(sum, d);
  const float inv = 1.f / (sqrtf(sum) + 1e-8f);
  *(ushort4*)(outRowB + lane * 4) =
      make_ushort4(f2bf(v.x * inv), f2bf(v.y * inv), f2bf(v.z * inv), f2bf(v.w * inv));
}

// ---------------- MFMA GEMM (256t x 128j, BK=32) + fused dual argmax ----------------
struct Smem {
  char bufs[2][24576];   // per buf: A [256][64B] @0, B [128][64B] @16384
  float tc[512];         // t coords: x [0,256), y [256,512)
  float jc[256];         // j coords: x [0,128), y [128,256)
  uint2 red[4][128];     // cross-wave (wr) reduce
};                       // 56,320 B -> 2 blocks/CU

__global__ __launch_bounds__(512, 4)
void k_mfma_argmax(const unsigned short* __restrict__ tarB,
                   const unsigned short* __restrict__ refB,
                   const float* __restrict__ un, const int* __restrict__ relax,
                   uint2* __restrict__ partial) {
  __shared__ Smem sm;
  const int tid = threadIdx.x;
  const int lane = tid & 63;
  const int wid = tid >> 6;

  // XCD swizzle (2888 % 8 == 0)
  const int bid = blockIdx.x;
  const int item = (bid & 7) * (NBLK / 8) + (bid >> 3);
  const int b = item / (NTJ * NTT);
  const int r2 = item - b * (NTJ * NTT);
  const int jt = r2 / NTT, tt = r2 % NTT;
  const int tbase = tt * BT, jbase = jt * BJ;
  const float* unb = un + (size_t)b * 2 * NP;

  // stage coords into LDS (before first barrier)
  {
    const int i = tid & 255;
    const int tg = tbase + i < NP ? tbase + i : NP - 1;
    sm.tc[tid] = unb[(tid < 256 ? 0 : NP) + tg];
    if (tid < 256) {
      const int i2 = tid & 127;
      const int jg = jbase + i2 < NP ? jbase + i2 : NP - 1;
      sm.jc[tid] = unb[(tid < 128 ? 0 : NP) + jg];
    }
  }

  // staging: waves 0-3 -> A (64 rows each), waves 4-7 -> B (32 rows each)
  const char* aSrc = (const char*)(tarB + ((size_t)b * NPAD + tbase) * CDIM);
  const char* bSrc = (const char*)(refB + ((size_t)b * NPAD + jbase) * CDIM);
  const char* gl; int ldsOff, nq;
  if (wid < 4) {
    gl = aSrc + (size_t)(wid * 64 + (lane >> 2)) * 512 + (lane & 3) * 16;
    ldsOff = wid * 4096; nq = 4;
  } else {
    gl = bSrc + (size_t)((wid - 4) * 32 + (lane >> 2)) * 512 + (lane & 3) * 16;
    ldsOff = 16384 + (wid - 4) * 2048; nq = 2;
  }

#define STAGE(buf, kb) do { \
    char* ldst = sm.bufs[buf] + ldsOff; \
    const char* gsp = gl + (kb) * 64; \
    _Pragma("unroll") for (int qq = 0; qq < 4; ++qq) \
      if (qq < nq) GLD16(ldst + qq * 1024, gsp + (size_t)qq * 8192); \
  } while (0)

  const int wr = wid >> 1, wc = wid & 1;   // wave: 64t x 64j
  const int l15 = lane & 15, h = lane >> 4;

  f32x4 acc[4][4];
#pragma unroll
  for (int fa = 0; fa < 4; ++fa)
#pragma unroll
    for (int fb = 0; fb < 4; ++fb) acc[fa][fb] = (f32x4){0.f, 0.f, 0.f, 0.f};

  STAGE(0, 0);
  __syncthreads();
  for (int kb = 0; kb < 8; ++kb) {   // K = 256 = 8 * 32
    const int buf = kb & 1;
    if (kb < 7) STAGE(buf ^ 1, kb + 1);   // issue next-tile loads before compute
    const char* ab = sm.bufs[buf];
    const char* bb = ab + 16384;
    bf16x8 af[4], bg[4];
#pragma unroll
    for (int fa = 0; fa < 4; ++fa)
      af[fa] = *(const bf16x8*)(ab + (wr * 64 + fa * 16 + l15) * 64 + h * 16);
#pragma unroll
    for (int fb = 0; fb < 4; ++fb)
      bg[fb] = *(const bf16x8*)(bb + (wc * 64 + fb * 16 + l15) * 64 + h * 16);
#pragma unroll
    for (int fa = 0; fa < 4; ++fa)
#pragma unroll
      for (int fb = 0; fb < 4; ++fb)
        acc[fa][fb] = __builtin_amdgcn_mfma_f32_16x16x32_bf16(af[fa], bg[fb], acc[fa][fb], 0, 0, 0);
    __syncthreads();
  }

  // ---- epilogue: packed-key dual argmax (u32: [31:13]=value bits, [12:0]=8191-t) ----
  const float rf = (float)relax[0];
  float jx[4], jy[4];
#pragma unroll
  for (int fb = 0; fb < 4; ++fb) {
    const int jl = wc * 64 + fb * 16 + l15;
    jx[fb] = sm.jc[jl]; jy[fb] = sm.jc[128 + jl];
  }
  unsigned int kA[4] = {0u, 0u, 0u, 0u}, kI[4] = {0u, 0u, 0u, 0u};
#pragma unroll
  for (int fa = 0; fa < 4; ++fa) {
#pragma unroll
    for (int i = 0; i < 4; ++i) {
      const int tl = wr * 64 + fa * 16 + h * 4 + i;
      const int t = tbase + tl;
      const float tx = sm.tc[tl], ty = sm.tc[256 + tl];
      const unsigned int tinv = (unsigned int)(8191 - t);
      const bool okT = (t < NP);
#pragma unroll
      for (int fb = 0; fb < 4; ++fb) {
        const unsigned int key =
            okT ? ((__float_as_uint(acc[fa][fb][i] + 2.f) & 0xFFFFE000u) | tinv) : 0u;
        if (key > kA[fb]) kA[fb] = key;
        const bool corr = (fabsf(tx - jx[fb]) <= rf) && (fabsf(ty - jy[fb]) <= rf);
        const unsigned int keyI = corr ? 0u : key;
        if (keyI > kI[fb]) kI[fb] = keyI;
      }
    }
  }
  // reduce over the 4 h-groups (disjoint t subsets, same j)
#pragma unroll
  for (int fb = 0; fb < 4; ++fb) {
#pragma unroll
    for (int d = 16; d < 64; d <<= 1) {
      const unsigned int oA = __shfl_xor(kA[fb], d);
      const unsigned int oI = __shfl_xor(kI[fb], d);
      if (oA > kA[fb]) kA[fb] = oA;
      if (oI > kI[fb]) kI[fb] = oI;
    }
    if (h == 0) sm.red[wr][wc * 64 + fb * 16 + l15] = make_uint2(kA[fb], kI[fb]);
  }
  __syncthreads();
  if (tid < 128) {
    const int jg = jbase + tid;
    if (jg < NP) {
      unsigned int a = sm.red[0][tid].x, c = sm.red[0][tid].y;
#pragma unroll
      for (int g = 1; g < 4; ++g) {
        if (sm.red[g][tid].x > a) a = sm.red[g][tid].x;
        if (sm.red[g][tid].y > c) c = sm.red[g][tid].y;
      }
      partial[((size_t)b * NP + jg) * NTT + tt] = make_uint2(a, c);
    }
  }
#undef STAGE
}

// ---------------- fused combine + per-point loss + recall (wave per point) ----------------
__global__ __launch_bounds__(256)
void k_loss(const unsigned short* __restrict__ refB, const unsigned short* __restrict__ tarB,
            const float* __restrict__ un, const uint2* __restrict__ partial,
            float* __restrict__ loss_arr, float* __restrict__ rec_arr) {
  const int w = threadIdx.x >> 6, lane = threadIdx.x & 63;
  const int n = blockIdx.x * 4 + w;
  const int b = blockIdx.y;
  const int bn = b * NP + n;
  unsigned int kA = 0u, kI = 0u;
  if (lane < NTT) {
    const uint2 p = partial[(size_t)bn * NTT + lane];
    kA = p.x; kI = p.y;
  }
#pragma unroll
  for (int d = 1; d < 64; d <<= 1) {
    const unsigned int oA = __shfl_xor(kA, d);
    const unsigned int oI = __shfl_xor(kI, d);
    if (oA > kA) kA = oA;
    if (oI > kI) kI = oI;
  }
  const int nn  = 8191 - (int)(kA & 0x1FFFu);
  const int neg = 8191 - (int)(kI & 0x1FFFu);
  const ushort4 rv = *(const ushort4*)(refB + ((size_t)b * NPAD + n) * CDIM + lane * 4);
  const ushort4 tv = *(const ushort4*)(tarB + ((size_t)b * NPAD + n) * CDIM + lane * 4);
  const ushort4 gv = *(const ushort4*)(tarB + ((size_t)b * NPAD + neg) * CDIM + lane * 4);
  float dp = 0.f, dn = 0.f, d;
  d = bf2f(rv.x) - bf2f(tv.x) + 1e-6f; dp += d * d;
  d = bf2f(rv.y) - bf2f(tv.y) + 1e-6f; dp += d * d;
  d = bf2f(rv.z) - bf2f(tv.z) + 1e-6f; dp += d * d;
  d = bf2f(rv.w) - bf2f(tv.w) + 1e-6f; dp += d * d;
  d = bf2f(rv.x) - bf2f(gv.x) + 1e-6f; dn += d * d;
  d = bf2f(rv.y) - bf2f(gv.y) + 1e-6f; dn += d * d;
  d = bf2f(rv.z) - bf2f(gv.z) + 1e-6f; dn += d * d;
  d = bf2f(rv.w) - bf2f(gv.w) + 1e-6f; dn += d * d;
#pragma unroll
  for (int off = 1; off < 64; off <<= 1) {
    dp += __shfl_xor(dp, off);
    dn += __shfl_xor(dn, off);
  }
  if (lane == 0) {
    const float loss = fmaxf(sqrtf(dp) - sqrtf(dn) + 0.2f, 0.f);
    const float* unb = un + (size_t)b * 2 * NP;
    const float rec = (unb[nn] == unb[n] && unb[NP + nn] == unb[NP + n]) ? 1.f : 0.f;
    loss_arr[bn] = loss;
    rec_arr[bn] = rec;
  }
}

// ---------------- final deterministic reduce ----------------
__global__ __launch_bounds__(256)
void k_finalize(const float* __restrict__ loss_arr, const float* __restrict__ rec_arr,
                float* __restrict__ out) {
  __shared__ float l[256], rr[256];
  float ls = 0.f, rs = 0.f;
  for (int i = threadIdx.x; i < BQ * NP; i += 256) { ls += loss_arr[i]; rs += rec_arr[i]; }
  l[threadIdx.x] = ls;
  rr[threadIdx.x] = rs;
  __syncthreads();
  for (int s = 128; s > 0; s >>= 1) {
    if (threadIdx.x < s) { l[threadIdx.x] += l[threadIdx.x + s]; rr[threadIdx.x] += rr[threadIdx.x + s]; }
    __syncthreads();
  }
  if (threadIdx.x == 0) {
    out[0] = l[0] / (float)(BQ * NP);
    out[1] = rr[0] / (float)(BQ * NP);
  }
}

extern "C" void kernel_launch(void* const* d_in, const int* in_sizes, int n_in,
                              void* d_out, int out_size, void* d_ws, size_t ws_size,
                              hipStream_t stream) {
  const float* src  = (const float*)d_in[0];
  const float* tgt  = (const float*)d_in[1];
  const float* spts = (const float*)d_in[2];
  const float* tpts = (const float*)d_in[3];
  const float* un   = (const float*)d_in[4];
  const int* relax  = (const int*)d_in[5];

  char* ws = (char*)d_ws;
  float*          desT     = (float*)(ws + WS_DEST);
  uint2*          partial  = (uint2*)(ws + WS_PART);   // aliases desT (dead by then)
  unsigned short* refB     = (unsigned short*)(ws + WS_REFB);
  unsigned short* tarB     = (unsigned short*)(ws + WS_TARB);
  float*          loss_arr = (float*)(ws + WS_LOSS);
  float*          rec_arr  = (float*)(ws + WS_REC);
  float*          out      = (float*)d_out;

  k_transpose<<<dim3(NP / 32, CDIM / 32, 8), dim3(32, 8), 0, stream>>>(src, tgt, desT);
  k_sample<<<dim3(NPAD / 4, BQ, 2), 256, 0, stream>>>(desT, spts, tpts, refB, tarB);
  k_mfma_argmax<<<NBLK, 512, 0, stream>>>(tarB, refB, un, relax, partial);
  k_loss<<<dim3(NP / 4, BQ), 256, 0, stream>>>(refB, tarB, un, partial, loss_arr, rec_arr);
  k_finalize<<<1, 256, 0, stream>>>(loss_arr, rec_arr, out);
}

// Round 5
// 127.631 us; speedup vs baseline: 26.9109x; 1.1314x over previous
//
#include <hip/hip_runtime.h>
#include <cstdint>
#include <cstddef>

// Problem constants: B=4, C=256, H=60, W=80, N=4800
#define BQ 4
#define CDIM 256
#define HH 60
#define WW 80
#define NP 4800
#define NPAD 4864          // lcm pad: 38*128 = 19*256
#define BT 256             // tile rows (t, A = tar)
#define BJ 128             // tile cols (j, B = ref)
#define BK 32              // K sub-tile
#define NTT 19             // t tiles (256)
#define NTJ 38             // j tiles (128)
#define NBLK (BQ * NTJ * NTT)   // 2888, %8==0

typedef __bf16 bf16x8 __attribute__((ext_vector_type(8)));
typedef float f32x4 __attribute__((ext_vector_type(4)));

// ---------------- ws layout (bytes) ----------------
#define WS_DEST 0              // bf16 2*4*4800*256*2 = 19,660,800 (dead after k_sample)
#define WS_PART 0              // uint2 4*4800*19*8 = 2,918,400 (aliases desT)
#define WS_REFB 19660800       // bf16 4*4864*256*2 = 9,961,472
#define WS_TARB 29622272       // bf16                9,961,472
#define WS_LOSS 39583744       // f32 19200 = 76,800
#define WS_REC  39660544       // f32 19200
// end 39,737,344

#define GLD16(dst, src) __builtin_amdgcn_global_load_lds( \
    (const __attribute__((address_space(1))) void*)(src), \
    (__attribute__((address_space(3))) void*)(dst), 16, 0, 0)

__device__ inline unsigned short f2bf(float f) {
  unsigned int u = __float_as_uint(f);
  return (unsigned short)((u + 0x7FFFu + ((u >> 16) & 1u)) >> 16);  // RNE
}
__device__ inline float bf2f(unsigned short s) {
  return __uint_as_float((unsigned int)s << 16);
}

// ---------------- transpose des (C, HW) f32 -> (HW, C) bf16 ----------------
// block: 64 channels x 32 hw, threads (32,8)
__global__ __launch_bounds__(256)
void k_transpose(const float* __restrict__ src, const float* __restrict__ tgt,
                 unsigned short* __restrict__ desT) {
  __shared__ float tile[64][33];
  const int z = blockIdx.z;  // tensor*4 + b
  const float* in = ((z >> 2) ? tgt : src) + (size_t)(z & 3) * CDIM * NP;
  unsigned short* out = desT + (size_t)z * NP * CDIM;
  const int hw0 = blockIdx.x * 32;
  const int c0 = blockIdx.y * 64;
  const int tx = threadIdx.x, ty = threadIdx.y;
#pragma unroll
  for (int q = 0; q < 8; ++q)
    tile[ty + q * 8][tx] = in[(size_t)(c0 + ty + q * 8) * NP + hw0 + tx];
  __syncthreads();
#pragma unroll
  for (int q = 0; q < 4; ++q) {
    const int hwl = ty + q * 8;
    *(ushort2*)(out + (size_t)(hw0 + hwl) * CDIM + c0 + 2 * tx) =
        make_ushort2(f2bf(tile[2 * tx][hwl]), f2bf(tile[2 * tx + 1][hwl]));
  }
}

// ---------------- bilinear sample + L2 normalize -> bf16 rows ----------------
__global__ __launch_bounds__(256)
void k_sample(const unsigned short* __restrict__ desT,
              const float* __restrict__ spts, const float* __restrict__ tpts,
              unsigned short* __restrict__ refB, unsigned short* __restrict__ tarB) {
  const int w = threadIdx.x >> 6, lane = threadIdx.x & 63;
  const int n = blockIdx.x * 4 + w;         // 0..NPAD-1
  const int b = blockIdx.y;
  const int tensor = blockIdx.z;            // 0: ref, 1: tar
  unsigned short* outRowB = (tensor ? tarB : refB) + ((size_t)b * NPAD + n) * CDIM;
  if (n >= NP) {  // zero pad rows (uniform per wave)
    *(ushort4*)(outRowB + lane * 4) = make_ushort4(0, 0, 0, 0);
    return;
  }
  const float* pts = (tensor ? tpts : spts) + ((size_t)b * NP + n) * 2;
  const float gx = pts[0], gy = pts[1];
  const float x = (gx + 1.f) * ((WW - 1) * 0.5f);
  const float y = (gy + 1.f) * ((HH - 1) * 0.5f);
  float x0f = fminf(fmaxf(floorf(x), 0.f), (float)(WW - 1));
  float y0f = fminf(fmaxf(floorf(y), 0.f), (float)(HH - 1));
  float x1f = fminf(x0f + 1.f, (float)(WW - 1));
  float y1f = fminf(y0f + 1.f, (float)(HH - 1));
  const float wx = x - x0f, wy = y - y0f;
  const int ix0 = (int)x0f, ix1 = (int)x1f, iy0 = (int)y0f, iy1 = (int)y1f;
  const unsigned short* base = desT + (size_t)(tensor * 4 + b) * NP * CDIM + lane * 4;
  const ushort4 u00 = *(const ushort4*)(base + (size_t)(iy0 * WW + ix0) * CDIM);
  const ushort4 u01 = *(const ushort4*)(base + (size_t)(iy0 * WW + ix1) * CDIM);
  const ushort4 u10 = *(const ushort4*)(base + (size_t)(iy1 * WW + ix0) * CDIM);
  const ushort4 u11 = *(const ushort4*)(base + (size_t)(iy1 * WW + ix1) * CDIM);
  const float w00 = (1.f - wx) * (1.f - wy), w01 = wx * (1.f - wy);
  const float w10 = (1.f - wx) * wy,         w11 = wx * wy;
  float4 v;
  v.x = bf2f(u00.x) * w00 + bf2f(u01.x) * w01 + bf2f(u10.x) * w10 + bf2f(u11.x) * w11;
  v.y = bf2f(u00.y) * w00 + bf2f(u01.y) * w01 + bf2f(u10.y) * w10 + bf2f(u11.y) * w11;
  v.z = bf2f(u00.z) * w00 + bf2f(u01.z) * w01 + bf2f(u10.z) * w10 + bf2f(u11.z) * w11;
  v.w = bf2f(u00.w) * w00 + bf2f(u01.w) * w01 + bf2f(u10.w) * w10 + bf2f(u11.w) * w11;
  float s0 = v.x + 1e-8f, s1 = v.y + 1e-8f, s2 = v.z + 1e-8f, s3 = v.w + 1e-8f;
  float sum = s0 * s0 + s1 * s1 + s2 * s2 + s3 * s3;
#pragma unroll
  for (int d = 1; d < 64; d <<= 1) sum += __shfl_xor(sum, d);
  const float inv = 1.f / (sqrtf(sum) + 1e-8f);
  *(ushort4*)(outRowB + lane * 4) =
      make_ushort4(f2bf(v.x * inv), f2bf(v.y * inv), f2bf(v.z * inv), f2bf(v.w * inv));
}

// ---------------- MFMA GEMM (256t x 128j, BK=32) + fused dual argmax ----------------
// LDS rows are 64 B (4 slots of 16 B). Zero-conflict swizzle: LDS[row][s] holds
// global slot s ^ ((row>>1)&3); any 8 consecutive reader lanes hit all 32 banks.
struct Smem {
  char bufs[2][24576];   // per buf: A [256][64B] @0, B [128][64B] @16384
  float tc[512];         // t coords: x [0,256), y [256,512)
  float jc[256];         // j coords: x [0,128), y [128,256)
  uint2 red[4][128];     // cross-wave (wr) reduce
};                       // 56,320 B -> 2 blocks/CU

__global__ __launch_bounds__(512, 4)
void k_mfma_argmax(const unsigned short* __restrict__ tarB,
                   const unsigned short* __restrict__ refB,
                   const float* __restrict__ un, const int* __restrict__ relax,
                   uint2* __restrict__ partial) {
  __shared__ Smem sm;
  const int tid = threadIdx.x;
  const int lane = tid & 63;
  const int wid = tid >> 6;

  // XCD swizzle (2888 % 8 == 0)
  const int bid = blockIdx.x;
  const int item = (bid & 7) * (NBLK / 8) + (bid >> 3);
  const int b = item / (NTJ * NTT);
  const int r2 = item - b * (NTJ * NTT);
  const int jt = r2 / NTT, tt = r2 % NTT;
  const int tbase = tt * BT, jbase = jt * BJ;
  const float* unb = un + (size_t)b * 2 * NP;

  // stage coords into LDS (before first barrier)
  {
    const int i = tid & 255;
    const int tg = tbase + i < NP ? tbase + i : NP - 1;
    sm.tc[tid] = unb[(tid < 256 ? 0 : NP) + tg];
    if (tid < 256) {
      const int i2 = tid & 127;
      const int jg = jbase + i2 < NP ? jbase + i2 : NP - 1;
      sm.jc[tid] = unb[(tid < 128 ? 0 : NP) + jg];
    }
  }

  // staging: waves 0-3 -> A (64 rows each), waves 4-7 -> B (32 rows each)
  // source slot pre-swizzled: (l&3) ^ ((l>>3)&3) == (l&3) ^ ((row>>1)&3)
  const char* aSrc = (const char*)(tarB + ((size_t)b * NPAD + tbase) * CDIM);
  const char* bSrc = (const char*)(refB + ((size_t)b * NPAD + jbase) * CDIM);
  const int srcSlot = ((lane & 3) ^ ((lane >> 3) & 3)) * 16;
  const char* gl; int ldsOff, nq;
  if (wid < 4) {
    gl = aSrc + (size_t)(wid * 64 + (lane >> 2)) * 512 + srcSlot;
    ldsOff = wid * 4096; nq = 4;
  } else {
    gl = bSrc + (size_t)((wid - 4) * 32 + (lane >> 2)) * 512 + srcSlot;
    ldsOff = 16384 + (wid - 4) * 2048; nq = 2;
  }

#define STAGE(buf, kb) do { \
    char* ldst = sm.bufs[buf] + ldsOff; \
    const char* gsp = gl + (kb) * 64; \
    _Pragma("unroll") for (int qq = 0; qq < 4; ++qq) \
      if (qq < nq) GLD16(ldst + qq * 1024, gsp + (size_t)qq * 8192); \
  } while (0)

  const int wr = wid >> 1, wc = wid & 1;   // wave: 64t x 64j
  const int l15 = lane & 15, h = lane >> 4;
  const int sx = (h ^ ((l15 >> 1) & 3)) << 4;   // swizzled read slot (per-thread const)

  f32x4 acc[4][4];
#pragma unroll
  for (int fa = 0; fa < 4; ++fa)
#pragma unroll
    for (int fb = 0; fb < 4; ++fb) acc[fa][fb] = (f32x4){0.f, 0.f, 0.f, 0.f};

  STAGE(0, 0);
  __syncthreads();
  for (int kb = 0; kb < 8; ++kb) {   // K = 256 = 8 * 32
    const int buf = kb & 1;
    if (kb < 7) STAGE(buf ^ 1, kb + 1);   // issue next-tile loads before compute
    const char* ab = sm.bufs[buf];
    const char* bb = ab + 16384;
    bf16x8 af[4], bg[4];
#pragma unroll
    for (int fa = 0; fa < 4; ++fa)
      af[fa] = *(const bf16x8*)(ab + (wr * 64 + fa * 16 + l15) * 64 + sx);
#pragma unroll
    for (int fb = 0; fb < 4; ++fb)
      bg[fb] = *(const bf16x8*)(bb + (wc * 64 + fb * 16 + l15) * 64 + sx);
#pragma unroll
    for (int fa = 0; fa < 4; ++fa)
#pragma unroll
      for (int fb = 0; fb < 4; ++fb)
        acc[fa][fb] = __builtin_amdgcn_mfma_f32_16x16x32_bf16(af[fa], bg[fb], acc[fa][fb], 0, 0, 0);
    __syncthreads();
  }

  // ---- epilogue: packed-key dual argmax (u32: [31:13]=value bits, [12:0]=8191-t) ----
  const float rf = (float)relax[0];
  float jx[4], jy[4];
#pragma unroll
  for (int fb = 0; fb < 4; ++fb) {
    const int jl = wc * 64 + fb * 16 + l15;
    jx[fb] = sm.jc[jl]; jy[fb] = sm.jc[128 + jl];
  }
  unsigned int kA[4] = {0u, 0u, 0u, 0u}, kI[4] = {0u, 0u, 0u, 0u};
#pragma unroll
  for (int fa = 0; fa < 4; ++fa) {
#pragma unroll
    for (int i = 0; i < 4; ++i) {
      const int tl = wr * 64 + fa * 16 + h * 4 + i;
      const int t = tbase + tl;
      const float tx = sm.tc[tl], ty = sm.tc[256 + tl];
      const unsigned int tinv = (unsigned int)(8191 - t);
      const bool okT = (t < NP);
#pragma unroll
      for (int fb = 0; fb < 4; ++fb) {
        const unsigned int key =
            okT ? ((__float_as_uint(acc[fa][fb][i] + 2.f) & 0xFFFFE000u) | tinv) : 0u;
        if (key > kA[fb]) kA[fb] = key;
        const bool corr = (fabsf(tx - jx[fb]) <= rf) && (fabsf(ty - jy[fb]) <= rf);
        const unsigned int keyI = corr ? 0u : key;
        if (keyI > kI[fb]) kI[fb] = keyI;
      }
    }
  }
  // reduce over the 4 h-groups (disjoint t subsets, same j)
#pragma unroll
  for (int fb = 0; fb < 4; ++fb) {
#pragma unroll
    for (int d = 16; d < 64; d <<= 1) {
      const unsigned int oA = __shfl_xor(kA[fb], d);
      const unsigned int oI = __shfl_xor(kI[fb], d);
      if (oA > kA[fb]) kA[fb] = oA;
      if (oI > kI[fb]) kI[fb] = oI;
    }
    if (h == 0) sm.red[wr][wc * 64 + fb * 16 + l15] = make_uint2(kA[fb], kI[fb]);
  }
  __syncthreads();
  if (tid < 128) {
    const int jg = jbase + tid;
    if (jg < NP) {
      unsigned int a = sm.red[0][tid].x, c = sm.red[0][tid].y;
#pragma unroll
      for (int g = 1; g < 4; ++g) {
        if (sm.red[g][tid].x > a) a = sm.red[g][tid].x;
        if (sm.red[g][tid].y > c) c = sm.red[g][tid].y;
      }
      partial[((size_t)b * NP + jg) * NTT + tt] = make_uint2(a, c);
    }
  }
#undef STAGE
}

// ---------------- fused combine + per-point loss + recall (wave per point) ----------------
__global__ __launch_bounds__(256)
void k_loss(const unsigned short* __restrict__ refB, const unsigned short* __restrict__ tarB,
            const float* __restrict__ un, const uint2* __restrict__ partial,
            float* __restrict__ loss_arr, float* __restrict__ rec_arr) {
  const int w = threadIdx.x >> 6, lane = threadIdx.x & 63;
  const int n = blockIdx.x * 4 + w;
  const int b = blockIdx.y;
  const int bn = b * NP + n;
  unsigned int kA = 0u, kI = 0u;
  if (lane < NTT) {
    const uint2 p = partial[(size_t)bn * NTT + lane];
    kA = p.x; kI = p.y;
  }
#pragma unroll
  for (int d = 1; d < 64; d <<= 1) {
    const unsigned int oA = __shfl_xor(kA, d);
    const unsigned int oI = __shfl_xor(kI, d);
    if (oA > kA) kA = oA;
    if (oI > kI) kI = oI;
  }
  const int nn  = 8191 - (int)(kA & 0x1FFFu);
  const int neg = 8191 - (int)(kI & 0x1FFFu);
  const ushort4 rv = *(const ushort4*)(refB + ((size_t)b * NPAD + n) * CDIM + lane * 4);
  const ushort4 tv = *(const ushort4*)(tarB + ((size_t)b * NPAD + n) * CDIM + lane * 4);
  const ushort4 gv = *(const ushort4*)(tarB + ((size_t)b * NPAD + neg) * CDIM + lane * 4);
  float dp = 0.f, dn = 0.f, d;
  d = bf2f(rv.x) - bf2f(tv.x) + 1e-6f; dp += d * d;
  d = bf2f(rv.y) - bf2f(tv.y) + 1e-6f; dp += d * d;
  d = bf2f(rv.z) - bf2f(tv.z) + 1e-6f; dp += d * d;
  d = bf2f(rv.w) - bf2f(tv.w) + 1e-6f; dp += d * d;
  d = bf2f(rv.x) - bf2f(gv.x) + 1e-6f; dn += d * d;
  d = bf2f(rv.y) - bf2f(gv.y) + 1e-6f; dn += d * d;
  d = bf2f(rv.z) - bf2f(gv.z) + 1e-6f; dn += d * d;
  d = bf2f(rv.w) - bf2f(gv.w) + 1e-6f; dn += d * d;
#pragma unroll
  for (int off = 1; off < 64; off <<= 1) {
    dp += __shfl_xor(dp, off);
    dn += __shfl_xor(dn, off);
  }
  if (lane == 0) {
    const float loss = fmaxf(sqrtf(dp) - sqrtf(dn) + 0.2f, 0.f);
    const float* unb = un + (size_t)b * 2 * NP;
    const float rec = (unb[nn] == unb[n] && unb[NP + nn] == unb[NP + n]) ? 1.f : 0.f;
    loss_arr[bn] = loss;
    rec_arr[bn] = rec;
  }
}

// ---------------- final deterministic reduce ----------------
__global__ __launch_bounds__(256)
void k_finalize(const float* __restrict__ loss_arr, const float* __restrict__ rec_arr,
                float* __restrict__ out) {
  __shared__ float l[256], rr[256];
  float ls = 0.f, rs = 0.f;
  for (int i = threadIdx.x; i < BQ * NP; i += 256) { ls += loss_arr[i]; rs += rec_arr[i]; }
  l[threadIdx.x] = ls;
  rr[threadIdx.x] = rs;
  __syncthreads();
  for (int s = 128; s > 0; s >>= 1) {
    if (threadIdx.x < s) { l[threadIdx.x] += l[threadIdx.x + s]; rr[threadIdx.x] += rr[threadIdx.x + s]; }
    __syncthreads();
  }
  if (threadIdx.x == 0) {
    out[0] = l[0] / (float)(BQ * NP);
    out[1] = rr[0] / (float)(BQ * NP);
  }
}

extern "C" void kernel_launch(void* const* d_in, const int* in_sizes, int n_in,
                              void* d_out, int out_size, void* d_ws, size_t ws_size,
                              hipStream_t stream) {
  const float* src  = (const float*)d_in[0];
  const float* tgt  = (const float*)d_in[1];
  const float* spts = (const float*)d_in[2];
  const float* tpts = (const float*)d_in[3];
  const float* un   = (const float*)d_in[4];
  const int* relax  = (const int*)d_in[5];

  char* ws = (char*)d_ws;
  unsigned short* desT     = (unsigned short*)(ws + WS_DEST);
  uint2*          partial  = (uint2*)(ws + WS_PART);   // aliases desT (dead by then)
  unsigned short* refB     = (unsigned short*)(ws + WS_REFB);
  unsigned short* tarB     = (unsigned short*)(ws + WS_TARB);
  float*          loss_arr = (float*)(ws + WS_LOSS);
  float*          rec_arr  = (float*)(ws + WS_REC);
  float*          out      = (float*)d_out;

  k_transpose<<<dim3(NP / 32, CDIM / 64, 8), dim3(32, 8), 0, stream>>>(src, tgt, desT);
  k_sample<<<dim3(NPAD / 4, BQ, 2), 256, 0, stream>>>(desT, spts, tpts, refB, tarB);
  k_mfma_argmax<<<NBLK, 512, 0, stream>>>(tarB, refB, un, relax, partial);
  k_loss<<<dim3(NP / 4, BQ), 256, 0, stream>>>(refB, tarB, un, partial, loss_arr, rec_arr);
  k_finalize<<<1, 256, 0, stream>>>(loss_arr, rec_arr, out);
}